// Round 12
// baseline (105.979 us; speedup 1.0000x reference)
//
#include <hip/hip_runtime.h>
#include <hip/hip_bf16.h>

#define N_NODES 10000
#define E_EDGES 320000
#define D 256
#define LRELU_ALPHA 0.2f

// fp32 world (round 3). dur_us includes ~56 us of harness re-poison fills
// (round-6 forensics). GEMM via mfma_f32_16x16x32_bf16 (round-8 win).
// Per-edge exp/score lane-parallel in prep (round-10 win); edata staged via
// wave-private LDS (round-11 win). Round 12: column-split aggregate — each
// pass gathers from a 2.56 MB half-table that fits per-XCD L2. Round-9's
// regression on this idea was confounded by 20-instr/edge overhead that
// rounds 10/11 removed (now ~7 instr/edge, ~1-2 us duplicated).

using short8  = __attribute__((ext_vector_type(8))) short;
using floatx4 = __attribute__((ext_vector_type(4))) float;
using bf16 = __hip_bfloat16;

__device__ __forceinline__ float bu2f(unsigned short u) {
    return __uint_as_float((unsigned)u << 16);
}
__device__ __forceinline__ unsigned short f2bu(float f) {
    union { bf16 b; unsigned short u; } cv;
    cv.b = __float2bfloat16(f);
    return cv.u;
}

// ---------------------------------------------------------------------------
// K1: W1 -> bf16 in MFMA B-fragment order.
// W1f[((s*16+t)*64+l)*8+j] = bf16(W1[k*D+n]), k = s*32+(l>>4)*8+j,
// n = t*16+(l&15). [B layout n=lane&15, k=quad*8+j — m89-verified]
// ---------------------------------------------------------------------------
__global__ __launch_bounds__(256) void wprep(const float* __restrict__ W1,
                                             bf16* __restrict__ W1f) {
    const int id = blockIdx.x * 256 + threadIdx.x;  // 65536 exact
    const int j = id & 7, l = (id >> 3) & 63, t = (id >> 9) & 15, s = id >> 13;
    const int k = s * 32 + (l >> 4) * 8 + j;
    const int n = t * 16 + (l & 15);
    W1f[id] = __float2bfloat16(W1[k * D + n]);
}

// ---------------------------------------------------------------------------
// K2: feats = X @ W1 + b1 via v_mfma_f32_16x16x32_bf16, fp32 accumulate.
// X read fp32, converted to bf16 A-frags inline. 625 blocks x 16 rows.
// Wave w owns cols 64w..64w+63; 32 MFMA/wave. Epilogue: +bias, bf16 feats
// store, fused a_src/a_dst row-dots from fp32 accumulators.
// D layout: col=lane&15, row=quad*4+reg (m89/m91-verified).
// ---------------------------------------------------------------------------
__global__ __launch_bounds__(256) void gemm_mfma(const float* __restrict__ X,
                                                 const bf16* __restrict__ W1f,
                                                 const float* __restrict__ b1,
                                                 const float* __restrict__ Wa,
                                                 bf16* __restrict__ featsb,
                                                 float* __restrict__ a_src,
                                                 float* __restrict__ a_dst) {
    const int w = threadIdx.x >> 6, l = threadIdx.x & 63;
    const int quad = l >> 4, lan = l & 15;
    const int row0 = blockIdx.x * 16;

    floatx4 acc[4] = {{0.f, 0.f, 0.f, 0.f}, {0.f, 0.f, 0.f, 0.f},
                      {0.f, 0.f, 0.f, 0.f}, {0.f, 0.f, 0.f, 0.f}};

    const float4* Ax = (const float4*)(X + (size_t)(row0 + lan) * D);
    const short8* B8 = (const short8*)W1f;

    #pragma unroll
    for (int s = 0; s < 8; ++s) {
        const float4 u = Ax[s * 8 + quad * 2];
        const float4 v = Ax[s * 8 + quad * 2 + 1];
        short8 af;
        af[0] = (short)f2bu(u.x); af[1] = (short)f2bu(u.y);
        af[2] = (short)f2bu(u.z); af[3] = (short)f2bu(u.w);
        af[4] = (short)f2bu(v.x); af[5] = (short)f2bu(v.y);
        af[6] = (short)f2bu(v.z); af[7] = (short)f2bu(v.w);
        #pragma unroll
        for (int t = 0; t < 4; ++t) {
            const short8 bf = B8[(s * 16 + (4 * w + t)) * 64 + l];
            acc[t] = __builtin_amdgcn_mfma_f32_16x16x32_bf16(af, bf, acc[t], 0, 0, 0);
        }
    }

    float p1[4] = {0.f, 0.f, 0.f, 0.f}, p2[4] = {0.f, 0.f, 0.f, 0.f};
    #pragma unroll
    for (int t = 0; t < 4; ++t) {
        const int n = (4 * w + t) * 16 + lan;
        const float bias = b1[n], wa1 = Wa[n], wa2 = Wa[D + n];
        #pragma unroll
        for (int r = 0; r < 4; ++r) {
            const float v = acc[t][r] + bias;
            featsb[(size_t)(row0 + quad * 4 + r) * D + n] = __float2bfloat16(v);
            p1[r] += v * wa1;
            p2[r] += v * wa2;
        }
    }

    __shared__ float red1[4][16], red2[4][16];
    #pragma unroll
    for (int r = 0; r < 4; ++r) {
        #pragma unroll
        for (int off = 1; off < 16; off <<= 1) {
            p1[r] += __shfl_xor(p1[r], off);
            p2[r] += __shfl_xor(p2[r], off);
        }
        if (lan == 0) { red1[w][quad * 4 + r] = p1[r]; red2[w][quad * 4 + r] = p2[r]; }
    }
    __syncthreads();
    if (threadIdx.x < 16) {
        const int m = threadIdx.x;
        a_src[row0 + m] = red1[0][m] + red1[1][m] + red1[2][m] + red1[3][m];
        a_dst[row0 + m] = red2[0][m] + red2[1][m] + red2[2][m] + red2[3][m];
    }
}

// ---------------------------------------------------------------------------
// K3: edges -> CSR row_start + packed per-edge (dst_byte_offset, exp(lrelu)).
// One edge per THREAD (lane-parallel score math — round-10 win). Edge words
// loaded as one int4/int2 per edge; sprev via __shfl_up (E = 1250*256
// exactly, all lanes active). a_src[s] coalesced; a_dst 40 KB (L1/L2).
// ---------------------------------------------------------------------------
__global__ __launch_bounds__(256) void prep(const int* __restrict__ raw,
                                            const float* __restrict__ a_src,
                                            const float* __restrict__ a_dst,
                                            const float* __restrict__ ba,
                                            int2* __restrict__ edata,
                                            int* __restrict__ row_start) {
    bool is64 = true;  // int64 rows: [s_lo, s_hi, d_lo, d_hi], hi words == 0
    #pragma unroll
    for (int t = 0; t < 16; ++t)
        if (raw[2 * t + 1] != 0) is64 = false;

    const int e = blockIdx.x * 256 + threadIdx.x;  // E = 1250*256 exact
    int s, d;
    if (is64) {
        const int4 v = ((const int4*)raw)[e];
        s = v.x; d = v.z;
    } else {
        const int2 v = ((const int2*)raw)[e];
        s = v.x; d = v.y;
    }
    // sprev: previous edge's src (wave shuffle; lane 0 falls back to a load)
    int sprev = __shfl_up(s, 1);
    if ((threadIdx.x & 63) == 0)
        sprev = (e == 0) ? -1 : raw[is64 ? (4 * e - 4) : (2 * e - 2)];

    float sc = a_src[s] + a_dst[d] + ba[0];
    sc = (sc > 0.f) ? sc : LRELU_ALPHA * sc;
    edata[e] = make_int2(d << 9, __float_as_int(expf(sc)));  // d*512 byte offset

    for (int r = sprev + 1; r <= s; ++r) row_start[r] = e;
    if (e == E_EDGES - 1)
        for (int r = s + 1; r <= N_NODES; ++r) row_start[r] = E_EDGES;
}

// ---------------------------------------------------------------------------
// K4: out[i, half*128 : half*128+128] — one column-half per launch so the
// gathered table footprint is 2.56 MB (fits every XCD's 4 MB L2). Two
// sequential launches give temporal separation. One WAVE per node; lane l
// owns cols half*128+2l, 2l+1 (uint = 2 bf16, 4 B/lane, 256 B/wave gather).
// edata staged via wave-private LDS (round-11 win; ~7 instr/edge/pass).
// dsum & scale wave-uniform (round-4 lesson). Ascending edge order ->
// bit-identical output vs round 11.
// ---------------------------------------------------------------------------
__global__ __launch_bounds__(256) void aggregate_half(const int2* __restrict__ edata,
                                                      const int* __restrict__ row_start,
                                                      const unsigned short* __restrict__ featsb,
                                                      float* __restrict__ out,
                                                      const int half) {
    __shared__ int2 els[4][64];
    const int wv = threadIdx.x >> 6, l = threadIdx.x & 63;
    const int i = blockIdx.x * 4 + wv;  // N_NODES % 4 == 0
    const int rs = row_start[i], re = row_start[i + 1];
    const char* Fb = (const char*)featsb + half * 256 + l * 4;

    float2 acc = {0.f, 0.f};
    float dsum = 0.f;

    for (int e = rs; e < re; e += 64) {
        const int cnt = min(64, re - e);
        if (l < cnt) els[wv][l] = edata[e + l];
        __builtin_amdgcn_wave_barrier();  // keep write before reads in sched

        int j = 0;
        for (; j + 8 <= cnt; j += 8) {
            #pragma unroll
            for (int u = 0; u < 8; ++u) {
                const int2 ed = els[wv][j + u];
                const unsigned int f = *(const unsigned int*)(Fb + (size_t)(unsigned)ed.x);
                const float x = __int_as_float(ed.y);
                acc.x += x * bu2f((unsigned short)(f & 0xffff));
                acc.y += x * bu2f((unsigned short)(f >> 16));
                dsum += x;
            }
        }
        for (; j < cnt; ++j) {
            const int2 ed = els[wv][j];
            const unsigned int f = *(const unsigned int*)(Fb + (size_t)(unsigned)ed.x);
            const float x = __int_as_float(ed.y);
            acc.x += x * bu2f((unsigned short)(f & 0xffff));
            acc.y += x * bu2f((unsigned short)(f >> 16));
            dsum += x;
        }
        __builtin_amdgcn_wave_barrier();  // next batch's write after reads
    }

    const float inv = (re > rs) ? 1.f / dsum : 0.f;  // wave-uniform
    float2 o;
    o.x = acc.x * inv;
    o.y = acc.y * inv;
    ((float2*)(out + (size_t)i * D + half * 128))[l] = o;
}

// ---------------------------------------------------------------------------
extern "C" void kernel_launch(void* const* d_in, const int* in_sizes, int n_in,
                              void* d_out, int out_size, void* d_ws, size_t ws_size,
                              hipStream_t stream) {
    const float* X     = (const float*)d_in[0];
    const int*   edges = (const int*)d_in[1];
    const float* W1    = (const float*)d_in[2];
    const float* b1    = (const float*)d_in[3];
    const float* Wa    = (const float*)d_in[4];
    const float* ba    = (const float*)d_in[5];
    float* out = (float*)d_out;

    // workspace carve-up (~8.5 MB), all 16 B aligned
    bf16* featsb = (bf16*)d_ws;                            // N*D bf16 = 5.12 MB
    bf16* W1f    = featsb + (size_t)N_NODES * D;           // 64K bf16 = 128 KB
    float* a_src = (float*)(W1f + 65536);                  // N
    float* a_dst = a_src + N_NODES;                        // N
    int2*  edata = (int2*)(a_dst + N_NODES);               // E int2 = 2.56 MB
    int*   row_start = (int*)(edata + E_EDGES);            // N+1

    wprep<<<65536 / 256, 256, 0, stream>>>(W1, W1f);
    gemm_mfma<<<N_NODES / 16, 256, 0, stream>>>(X, W1f, b1, Wa, featsb, a_src, a_dst);
    prep<<<E_EDGES / 256, 256, 0, stream>>>(edges, a_src, a_dst, ba, edata, row_start);
    aggregate_half<<<N_NODES / 4, 256, 0, stream>>>(edata, row_start,
                                                    (const unsigned short*)featsb, out, 0);
    aggregate_half<<<N_NODES / 4, 256, 0, stream>>>(edata, row_start,
                                                    (const unsigned short*)featsb, out, 1);
}

// Round 13
// 104.068 us; speedup vs baseline: 1.0184x; 1.0184x over previous
//
#include <hip/hip_runtime.h>
#include <hip/hip_bf16.h>

#define N_NODES 10000
#define E_EDGES 320000
#define D 256
#define LRELU_ALPHA 0.2f

// fp32 world (round 3). dur_us includes ~50 us of harness re-poison fills
// (round-6 forensics). GEMM via mfma_f32_16x16x32_bf16 (round-8 win).
// Per-edge exp/score lane-parallel in prep (round-10 win); edata staged via
// wave-private LDS (round-11 win). L2 column-split REGRESSED twice (R9, R12)
// -> gather locality is NOT the limiter; vmem issue count is. Round 13:
// 16 B/lane gathers -> one vmem instruction covers TWO edges.

using short8  = __attribute__((ext_vector_type(8))) short;
using floatx4 = __attribute__((ext_vector_type(4))) float;
using bf16 = __hip_bfloat16;

__device__ __forceinline__ float bu2f(unsigned int u) {
    return __uint_as_float(u << 16);  // low 16 bits = bf16 pattern
}
__device__ __forceinline__ unsigned short f2bu(float f) {
    union { bf16 b; unsigned short u; } cv;
    cv.b = __float2bfloat16(f);
    return cv.u;
}

// ---------------------------------------------------------------------------
// K1: W1 -> bf16 in MFMA B-fragment order.
// W1f[((s*16+t)*64+l)*8+j] = bf16(W1[k*D+n]), k = s*32+(l>>4)*8+j,
// n = t*16+(l&15). [B layout n=lane&15, k=quad*8+j — m89-verified]
// ---------------------------------------------------------------------------
__global__ __launch_bounds__(256) void wprep(const float* __restrict__ W1,
                                             bf16* __restrict__ W1f) {
    const int id = blockIdx.x * 256 + threadIdx.x;  // 65536 exact
    const int j = id & 7, l = (id >> 3) & 63, t = (id >> 9) & 15, s = id >> 13;
    const int k = s * 32 + (l >> 4) * 8 + j;
    const int n = t * 16 + (l & 15);
    W1f[id] = __float2bfloat16(W1[k * D + n]);
}

// ---------------------------------------------------------------------------
// K2: feats = X @ W1 + b1 via v_mfma_f32_16x16x32_bf16, fp32 accumulate.
// X read fp32, converted to bf16 A-frags inline. 625 blocks x 16 rows.
// Wave w owns cols 64w..64w+63; 32 MFMA/wave. Epilogue: +bias, bf16 feats
// store, fused a_src/a_dst row-dots from fp32 accumulators.
// D layout: col=lane&15, row=quad*4+reg (m89/m91-verified).
// ---------------------------------------------------------------------------
__global__ __launch_bounds__(256) void gemm_mfma(const float* __restrict__ X,
                                                 const bf16* __restrict__ W1f,
                                                 const float* __restrict__ b1,
                                                 const float* __restrict__ Wa,
                                                 bf16* __restrict__ featsb,
                                                 float* __restrict__ a_src,
                                                 float* __restrict__ a_dst) {
    const int w = threadIdx.x >> 6, l = threadIdx.x & 63;
    const int quad = l >> 4, lan = l & 15;
    const int row0 = blockIdx.x * 16;

    floatx4 acc[4] = {{0.f, 0.f, 0.f, 0.f}, {0.f, 0.f, 0.f, 0.f},
                      {0.f, 0.f, 0.f, 0.f}, {0.f, 0.f, 0.f, 0.f}};

    const float4* Ax = (const float4*)(X + (size_t)(row0 + lan) * D);
    const short8* B8 = (const short8*)W1f;

    #pragma unroll
    for (int s = 0; s < 8; ++s) {
        const float4 u = Ax[s * 8 + quad * 2];
        const float4 v = Ax[s * 8 + quad * 2 + 1];
        short8 af;
        af[0] = (short)f2bu(u.x); af[1] = (short)f2bu(u.y);
        af[2] = (short)f2bu(u.z); af[3] = (short)f2bu(u.w);
        af[4] = (short)f2bu(v.x); af[5] = (short)f2bu(v.y);
        af[6] = (short)f2bu(v.z); af[7] = (short)f2bu(v.w);
        #pragma unroll
        for (int t = 0; t < 4; ++t) {
            const short8 bf = B8[(s * 16 + (4 * w + t)) * 64 + l];
            acc[t] = __builtin_amdgcn_mfma_f32_16x16x32_bf16(af, bf, acc[t], 0, 0, 0);
        }
    }

    float p1[4] = {0.f, 0.f, 0.f, 0.f}, p2[4] = {0.f, 0.f, 0.f, 0.f};
    #pragma unroll
    for (int t = 0; t < 4; ++t) {
        const int n = (4 * w + t) * 16 + lan;
        const float bias = b1[n], wa1 = Wa[n], wa2 = Wa[D + n];
        #pragma unroll
        for (int r = 0; r < 4; ++r) {
            const float v = acc[t][r] + bias;
            featsb[(size_t)(row0 + quad * 4 + r) * D + n] = __float2bfloat16(v);
            p1[r] += v * wa1;
            p2[r] += v * wa2;
        }
    }

    __shared__ float red1[4][16], red2[4][16];
    #pragma unroll
    for (int r = 0; r < 4; ++r) {
        #pragma unroll
        for (int off = 1; off < 16; off <<= 1) {
            p1[r] += __shfl_xor(p1[r], off);
            p2[r] += __shfl_xor(p2[r], off);
        }
        if (lan == 0) { red1[w][quad * 4 + r] = p1[r]; red2[w][quad * 4 + r] = p2[r]; }
    }
    __syncthreads();
    if (threadIdx.x < 16) {
        const int m = threadIdx.x;
        a_src[row0 + m] = red1[0][m] + red1[1][m] + red1[2][m] + red1[3][m];
        a_dst[row0 + m] = red2[0][m] + red2[1][m] + red2[2][m] + red2[3][m];
    }
}

// ---------------------------------------------------------------------------
// K3: edges -> CSR row_start + packed per-edge (dst_byte_offset, exp(lrelu)).
// One edge per THREAD (lane-parallel score math — round-10 win). Edge words
// loaded as one int4/int2 per edge; sprev via __shfl_up (E = 1250*256
// exactly, all lanes active). a_src[s] coalesced; a_dst 40 KB (L1/L2).
// ---------------------------------------------------------------------------
__global__ __launch_bounds__(256) void prep(const int* __restrict__ raw,
                                            const float* __restrict__ a_src,
                                            const float* __restrict__ a_dst,
                                            const float* __restrict__ ba,
                                            int2* __restrict__ edata,
                                            int* __restrict__ row_start) {
    bool is64 = true;  // int64 rows: [s_lo, s_hi, d_lo, d_hi], hi words == 0
    #pragma unroll
    for (int t = 0; t < 16; ++t)
        if (raw[2 * t + 1] != 0) is64 = false;

    const int e = blockIdx.x * 256 + threadIdx.x;  // E = 1250*256 exact
    int s, d;
    if (is64) {
        const int4 v = ((const int4*)raw)[e];
        s = v.x; d = v.z;
    } else {
        const int2 v = ((const int2*)raw)[e];
        s = v.x; d = v.y;
    }
    int sprev = __shfl_up(s, 1);
    if ((threadIdx.x & 63) == 0)
        sprev = (e == 0) ? -1 : raw[is64 ? (4 * e - 4) : (2 * e - 2)];

    float sc = a_src[s] + a_dst[d] + ba[0];
    sc = (sc > 0.f) ? sc : LRELU_ALPHA * sc;
    edata[e] = make_int2(d << 9, __float_as_int(expf(sc)));  // d*512 byte offset

    for (int r = sprev + 1; r <= s; ++r) row_start[r] = e;
    if (e == E_EDGES - 1)
        for (int r = s + 1; r <= N_NODES; ++r) row_start[r] = E_EDGES;
}

// ---------------------------------------------------------------------------
// K4: out[i,:] = (sum_e ex[e] * feats[dst[e],:]) / sum_e ex[e].
// One WAVE per node; lane half h=l>>5 owns EDGE j+h, col-block c=l&31
// (8 cols, 16 B dwordx4 gather) -> ONE vmem instruction covers TWO edges
// (1 KB). edata staged via wave-private LDS (round-11 win). Each half sums
// its own edge subset -> deliberate cross-half shfl_xor(32) combine of
// dsum + acc at the end (NOT the round-4 bug: halves are disjoint).
// Odd tail edge: dummy with x=0 (exact no-op).
// ---------------------------------------------------------------------------
__global__ __launch_bounds__(256) void aggregate(const int2* __restrict__ edata,
                                                 const int* __restrict__ row_start,
                                                 const unsigned short* __restrict__ featsb,
                                                 float* __restrict__ out) {
    __shared__ int2 els[4][64];
    const int wv = threadIdx.x >> 6, l = threadIdx.x & 63;
    const int h = l >> 5;   // which edge of the pair
    const int c = l & 31;   // col-block (8 cols)
    const int i = blockIdx.x * 4 + wv;  // N_NODES % 4 == 0
    const int rs = row_start[i], re = row_start[i + 1];
    const char* Fb = (const char*)featsb + c * 16;

    float acc[8] = {0.f, 0.f, 0.f, 0.f, 0.f, 0.f, 0.f, 0.f};
    float dsum = 0.f;

    for (int e = rs; e < re; e += 64) {
        const int cnt = min(64, re - e);
        if (l < cnt) els[wv][l] = edata[e + l];
        __builtin_amdgcn_wave_barrier();  // keep write before reads in sched

        int j = 0;
        for (; j + 16 <= cnt; j += 16) {  // 8 pairs unrolled = 8 loads in flight
            #pragma unroll
            for (int u = 0; u < 8; ++u) {
                const int2 ed = els[wv][j + 2 * u + h];
                const uint4 f = *(const uint4*)(Fb + (size_t)(unsigned)ed.x);
                const float x = __int_as_float(ed.y);
                acc[0] += x * bu2f(f.x & 0xffff); acc[1] += x * bu2f(f.x >> 16);
                acc[2] += x * bu2f(f.y & 0xffff); acc[3] += x * bu2f(f.y >> 16);
                acc[4] += x * bu2f(f.z & 0xffff); acc[5] += x * bu2f(f.z >> 16);
                acc[6] += x * bu2f(f.w & 0xffff); acc[7] += x * bu2f(f.w >> 16);
                dsum += x;
            }
        }
        for (; j < cnt; j += 2) {  // tail pairs (possibly one dummy edge)
            const int idx = j + h;
            const int2 ed = (idx < cnt) ? els[wv][idx] : make_int2(0, 0);
            const uint4 f = *(const uint4*)(Fb + (size_t)(unsigned)ed.x);
            const float x = __int_as_float(ed.y);  // 0.0f for dummy
            acc[0] += x * bu2f(f.x & 0xffff); acc[1] += x * bu2f(f.x >> 16);
            acc[2] += x * bu2f(f.y & 0xffff); acc[3] += x * bu2f(f.y >> 16);
            acc[4] += x * bu2f(f.z & 0xffff); acc[5] += x * bu2f(f.z >> 16);
            acc[6] += x * bu2f(f.w & 0xffff); acc[7] += x * bu2f(f.w >> 16);
            dsum += x;
        }
        __builtin_amdgcn_wave_barrier();  // next batch's write after reads
    }

    // combine the two disjoint edge-halves
    dsum += __shfl_xor(dsum, 32);
    #pragma unroll
    for (int q = 0; q < 8; ++q) acc[q] += __shfl_xor(acc[q], 32);

    const float inv = (re > rs) ? 1.f / dsum : 0.f;  // now wave-uniform
    float4 o;
    if (h == 0) { o.x = acc[0] * inv; o.y = acc[1] * inv; o.z = acc[2] * inv; o.w = acc[3] * inv; }
    else        { o.x = acc[4] * inv; o.y = acc[5] * inv; o.z = acc[6] * inv; o.w = acc[7] * inv; }
    *(float4*)(out + (size_t)i * D + c * 8 + h * 4) = o;
}

// ---------------------------------------------------------------------------
extern "C" void kernel_launch(void* const* d_in, const int* in_sizes, int n_in,
                              void* d_out, int out_size, void* d_ws, size_t ws_size,
                              hipStream_t stream) {
    const float* X     = (const float*)d_in[0];
    const int*   edges = (const int*)d_in[1];
    const float* W1    = (const float*)d_in[2];
    const float* b1    = (const float*)d_in[3];
    const float* Wa    = (const float*)d_in[4];
    const float* ba    = (const float*)d_in[5];
    float* out = (float*)d_out;

    // workspace carve-up (~8.5 MB), all 16 B aligned
    bf16* featsb = (bf16*)d_ws;                            // N*D bf16 = 5.12 MB
    bf16* W1f    = featsb + (size_t)N_NODES * D;           // 64K bf16 = 128 KB
    float* a_src = (float*)(W1f + 65536);                  // N
    float* a_dst = a_src + N_NODES;                        // N
    int2*  edata = (int2*)(a_dst + N_NODES);               // E int2 = 2.56 MB
    int*   row_start = (int*)(edata + E_EDGES);            // N+1

    wprep<<<65536 / 256, 256, 0, stream>>>(W1, W1f);
    gemm_mfma<<<N_NODES / 16, 256, 0, stream>>>(X, W1f, b1, Wa, featsb, a_src, a_dst);
    prep<<<E_EDGES / 256, 256, 0, stream>>>(edges, a_src, a_dst, ba, edata, row_start);
    aggregate<<<N_NODES / 4, 256, 0, stream>>>(edata, row_start,
                                               (const unsigned short*)featsb, out);
}

// Round 14
// 103.044 us; speedup vs baseline: 1.0285x; 1.0099x over previous
//
#include <hip/hip_runtime.h>
#include <hip/hip_bf16.h>

#define N_NODES 10000
#define E_EDGES 320000
#define D 256
#define LRELU_ALPHA 0.2f

// fp32 world (round 3). dur_us includes ~50 us of harness re-poison fills
// (round-6 forensics). GEMM via mfma_f32_16x16x32_bf16 (round-8 win).
// Per-edge exp/score lane-parallel in prep (round-10 win); edata staged via
// wave-private LDS (round-11 win). Aggregate plateau established by three
// falsified theories: L2 column-split regressed twice (R9 +13, R12 +3.2);
// pair-gather (2 edges/vmem, R13) neutral. This round: empirical best
// combination = R11 aggregate + R12 vectorized prep. ~10 us aggregate floor
// = LLC payload BW (164 MB) + per-edge issue minimum.

using short8  = __attribute__((ext_vector_type(8))) short;
using floatx4 = __attribute__((ext_vector_type(4))) float;
using bf16 = __hip_bfloat16;

__device__ __forceinline__ float bu2f(unsigned short u) {
    return __uint_as_float((unsigned)u << 16);
}
__device__ __forceinline__ unsigned short f2bu(float f) {
    union { bf16 b; unsigned short u; } cv;
    cv.b = __float2bfloat16(f);
    return cv.u;
}

// ---------------------------------------------------------------------------
// K1: W1 -> bf16 in MFMA B-fragment order.
// W1f[((s*16+t)*64+l)*8+j] = bf16(W1[k*D+n]), k = s*32+(l>>4)*8+j,
// n = t*16+(l&15). [B layout n=lane&15, k=quad*8+j — m89-verified]
// ---------------------------------------------------------------------------
__global__ __launch_bounds__(256) void wprep(const float* __restrict__ W1,
                                             bf16* __restrict__ W1f) {
    const int id = blockIdx.x * 256 + threadIdx.x;  // 65536 exact
    const int j = id & 7, l = (id >> 3) & 63, t = (id >> 9) & 15, s = id >> 13;
    const int k = s * 32 + (l >> 4) * 8 + j;
    const int n = t * 16 + (l & 15);
    W1f[id] = __float2bfloat16(W1[k * D + n]);
}

// ---------------------------------------------------------------------------
// K2: feats = X @ W1 + b1 via v_mfma_f32_16x16x32_bf16, fp32 accumulate.
// X read fp32, converted to bf16 A-frags inline. 625 blocks x 16 rows.
// Wave w owns cols 64w..64w+63; 32 MFMA/wave. Epilogue: +bias, bf16 feats
// store, fused a_src/a_dst row-dots from fp32 accumulators.
// D layout: col=lane&15, row=quad*4+reg (m89/m91-verified).
// ---------------------------------------------------------------------------
__global__ __launch_bounds__(256) void gemm_mfma(const float* __restrict__ X,
                                                 const bf16* __restrict__ W1f,
                                                 const float* __restrict__ b1,
                                                 const float* __restrict__ Wa,
                                                 bf16* __restrict__ featsb,
                                                 float* __restrict__ a_src,
                                                 float* __restrict__ a_dst) {
    const int w = threadIdx.x >> 6, l = threadIdx.x & 63;
    const int quad = l >> 4, lan = l & 15;
    const int row0 = blockIdx.x * 16;

    floatx4 acc[4] = {{0.f, 0.f, 0.f, 0.f}, {0.f, 0.f, 0.f, 0.f},
                      {0.f, 0.f, 0.f, 0.f}, {0.f, 0.f, 0.f, 0.f}};

    const float4* Ax = (const float4*)(X + (size_t)(row0 + lan) * D);
    const short8* B8 = (const short8*)W1f;

    #pragma unroll
    for (int s = 0; s < 8; ++s) {
        const float4 u = Ax[s * 8 + quad * 2];
        const float4 v = Ax[s * 8 + quad * 2 + 1];
        short8 af;
        af[0] = (short)f2bu(u.x); af[1] = (short)f2bu(u.y);
        af[2] = (short)f2bu(u.z); af[3] = (short)f2bu(u.w);
        af[4] = (short)f2bu(v.x); af[5] = (short)f2bu(v.y);
        af[6] = (short)f2bu(v.z); af[7] = (short)f2bu(v.w);
        #pragma unroll
        for (int t = 0; t < 4; ++t) {
            const short8 bf = B8[(s * 16 + (4 * w + t)) * 64 + l];
            acc[t] = __builtin_amdgcn_mfma_f32_16x16x32_bf16(af, bf, acc[t], 0, 0, 0);
        }
    }

    float p1[4] = {0.f, 0.f, 0.f, 0.f}, p2[4] = {0.f, 0.f, 0.f, 0.f};
    #pragma unroll
    for (int t = 0; t < 4; ++t) {
        const int n = (4 * w + t) * 16 + lan;
        const float bias = b1[n], wa1 = Wa[n], wa2 = Wa[D + n];
        #pragma unroll
        for (int r = 0; r < 4; ++r) {
            const float v = acc[t][r] + bias;
            featsb[(size_t)(row0 + quad * 4 + r) * D + n] = __float2bfloat16(v);
            p1[r] += v * wa1;
            p2[r] += v * wa2;
        }
    }

    __shared__ float red1[4][16], red2[4][16];
    #pragma unroll
    for (int r = 0; r < 4; ++r) {
        #pragma unroll
        for (int off = 1; off < 16; off <<= 1) {
            p1[r] += __shfl_xor(p1[r], off);
            p2[r] += __shfl_xor(p2[r], off);
        }
        if (lan == 0) { red1[w][quad * 4 + r] = p1[r]; red2[w][quad * 4 + r] = p2[r]; }
    }
    __syncthreads();
    if (threadIdx.x < 16) {
        const int m = threadIdx.x;
        a_src[row0 + m] = red1[0][m] + red1[1][m] + red1[2][m] + red1[3][m];
        a_dst[row0 + m] = red2[0][m] + red2[1][m] + red2[2][m] + red2[3][m];
    }
}

// ---------------------------------------------------------------------------
// K3: edges -> CSR row_start + packed per-edge (dst_byte_offset, exp(lrelu)).
// One edge per THREAD (lane-parallel score math — round-10 win). Edge words
// loaded as one int4/int2 per edge; sprev via __shfl_up (E = 1250*256
// exactly, all lanes active). a_src[s] coalesced; a_dst 40 KB (L1/L2).
// ---------------------------------------------------------------------------
__global__ __launch_bounds__(256) void prep(const int* __restrict__ raw,
                                            const float* __restrict__ a_src,
                                            const float* __restrict__ a_dst,
                                            const float* __restrict__ ba,
                                            int2* __restrict__ edata,
                                            int* __restrict__ row_start) {
    bool is64 = true;  // int64 rows: [s_lo, s_hi, d_lo, d_hi], hi words == 0
    #pragma unroll
    for (int t = 0; t < 16; ++t)
        if (raw[2 * t + 1] != 0) is64 = false;

    const int e = blockIdx.x * 256 + threadIdx.x;  // E = 1250*256 exact
    int s, d;
    if (is64) {
        const int4 v = ((const int4*)raw)[e];
        s = v.x; d = v.z;
    } else {
        const int2 v = ((const int2*)raw)[e];
        s = v.x; d = v.y;
    }
    int sprev = __shfl_up(s, 1);
    if ((threadIdx.x & 63) == 0)
        sprev = (e == 0) ? -1 : raw[is64 ? (4 * e - 4) : (2 * e - 2)];

    float sc = a_src[s] + a_dst[d] + ba[0];
    sc = (sc > 0.f) ? sc : LRELU_ALPHA * sc;
    edata[e] = make_int2(d << 9, __float_as_int(expf(sc)));  // d*512 byte offset

    for (int r = sprev + 1; r <= s; ++r) row_start[r] = e;
    if (e == E_EDGES - 1)
        for (int r = s + 1; r <= N_NODES; ++r) row_start[r] = E_EDGES;
}

// ---------------------------------------------------------------------------
// K4: out[i,:] = (sum_e ex[e] * feats[dst[e],:]) / sum_e ex[e].
// R11 version verbatim (best measured). One WAVE per node; lane l owns cols
// 4l..4l+3 (ushort4 bf16, 512 B/wave gather). Edge metadata staged through
// wave-private LDS: one coalesced 512 B load covers up to 64 edges.
// Same-wave LDS is in-order -> no __syncthreads. dsum & scale wave-uniform
// (round-4 lesson).
// ---------------------------------------------------------------------------
__global__ __launch_bounds__(256) void aggregate(const int2* __restrict__ edata,
                                                 const int* __restrict__ row_start,
                                                 const unsigned short* __restrict__ featsb,
                                                 float* __restrict__ out) {
    __shared__ int2 els[4][64];
    const int wv = threadIdx.x >> 6, l = threadIdx.x & 63;
    const int i = blockIdx.x * 4 + wv;  // N_NODES % 4 == 0
    const int rs = row_start[i], re = row_start[i + 1];
    const char* Fb = (const char*)featsb;

    float4 acc = {0.f, 0.f, 0.f, 0.f};
    float dsum = 0.f;

    for (int e = rs; e < re; e += 64) {
        const int cnt = min(64, re - e);
        if (l < cnt) els[wv][l] = edata[e + l];
        __builtin_amdgcn_wave_barrier();  // keep write before reads in sched

        int j = 0;
        for (; j + 8 <= cnt; j += 8) {
            #pragma unroll
            for (int u = 0; u < 8; ++u) {
                const int2 ed = els[wv][j + u];
                const ushort4 f = *(const ushort4*)(Fb + (size_t)(unsigned)ed.x + l * 8);
                const float x = __int_as_float(ed.y);
                acc.x += x * bu2f(f.x); acc.y += x * bu2f(f.y);
                acc.z += x * bu2f(f.z); acc.w += x * bu2f(f.w);
                dsum += x;
            }
        }
        for (; j < cnt; ++j) {
            const int2 ed = els[wv][j];
            const ushort4 f = *(const ushort4*)(Fb + (size_t)(unsigned)ed.x + l * 8);
            const float x = __int_as_float(ed.y);
            acc.x += x * bu2f(f.x); acc.y += x * bu2f(f.y);
            acc.z += x * bu2f(f.z); acc.w += x * bu2f(f.w);
            dsum += x;
        }
        __builtin_amdgcn_wave_barrier();  // next batch's write after reads
    }

    const float inv = (re > rs) ? 1.f / dsum : 0.f;  // wave-uniform
    float4 o;
    o.x = acc.x * inv; o.y = acc.y * inv; o.z = acc.z * inv; o.w = acc.w * inv;
    ((float4*)out)[(size_t)i * 64 + l] = o;
}

// ---------------------------------------------------------------------------
extern "C" void kernel_launch(void* const* d_in, const int* in_sizes, int n_in,
                              void* d_out, int out_size, void* d_ws, size_t ws_size,
                              hipStream_t stream) {
    const float* X     = (const float*)d_in[0];
    const int*   edges = (const int*)d_in[1];
    const float* W1    = (const float*)d_in[2];
    const float* b1    = (const float*)d_in[3];
    const float* Wa    = (const float*)d_in[4];
    const float* ba    = (const float*)d_in[5];
    float* out = (float*)d_out;

    // workspace carve-up (~8.5 MB), all 16 B aligned
    bf16* featsb = (bf16*)d_ws;                            // N*D bf16 = 5.12 MB
    bf16* W1f    = featsb + (size_t)N_NODES * D;           // 64K bf16 = 128 KB
    float* a_src = (float*)(W1f + 65536);                  // N
    float* a_dst = a_src + N_NODES;                        // N
    int2*  edata = (int2*)(a_dst + N_NODES);               // E int2 = 2.56 MB
    int*   row_start = (int*)(edata + E_EDGES);            // N+1

    wprep<<<65536 / 256, 256, 0, stream>>>(W1, W1f);
    gemm_mfma<<<N_NODES / 16, 256, 0, stream>>>(X, W1f, b1, Wa, featsb, a_src, a_dst);
    prep<<<E_EDGES / 256, 256, 0, stream>>>(edges, a_src, a_dst, ba, edata, row_start);
    aggregate<<<N_NODES / 4, 256, 0, stream>>>(edata, row_start,
                                               (const unsigned short*)featsb, out);
}